// Round 5
// baseline (165.653 us; speedup 1.0000x reference)
//
#include <hip/hip_runtime.h>
#include <math.h>

// Ising-style flip: out = s * flip where
//   Js = up+down+left+right (periodic, r=1); de = (2*s)*Js
//   p  = de<=0 ? 1 : exp(-de); flip = (rand<p)&&(drop>0.5) ? -1 : +1
// x, rand: (16,1,2048,2048) f32; drop: (2048,2048) f32.
//
// R5: vertical-sweep blocks. Each 256-thread block owns a half-row column
// strip and sweeps 4 vertically consecutive 4-row strips (16 rows). Boundary
// x rows carry over in REGISTERS (x demand 1.5x -> ~1.06x), and each iter
// prefetches the next strip's x+rand before computing the current one
// (software pipeline -> continuous MLP). XCD chunking: each XCD owns exactly
// 2 images; concurrent working set ~3MB fits its 4MB L2.

namespace {

constexpr int Bn = 16;
constexpr int Hn = 2048;
constexpr int Wn = 2048;
constexpr int IMG = Hn * Wn;
constexpr int NBLK = 4096;   // 16 img * 128 groups * 2 halves

typedef float f4 __attribute__((ext_vector_type(4)));

__device__ __forceinline__ int wrapr(int r) {
    return r < 0 ? r + Hn : (r >= Hn ? r - Hn : r);
}

__device__ __forceinline__ f4 flip_row(const f4 up, const f4 sc, const f4 dn,
                                       const f4 rv, const f4 dv,
                                       const float lf, const float rt)
{
    f4 o;
#pragma unroll
    for (int j = 0; j < 4; ++j) {
        const float s     = sc[j];
        const float left  = (j == 0) ? lf : sc[j - 1];
        const float right = (j == 3) ? rt : sc[j + 1];
        // Reference op order: Js = ((up+down)+left)+right; de = (2*s)*Js
        const float js = ((up[j] + dn[j]) + left) + right;
        const float de = (2.0f * s) * js;

        bool lt;
        if (de <= 0.0f) {
            lt = true;                    // p = 1; rand in [0,1) < 1
        } else {
            float p = expf(-de);
            // Tie band: near-equal rand vs p -> recompute exp in double to
            // match the host reference's correctly-rounded flip decision.
            if (fabsf(rv[j] - p) <= p * 1.0e-6f) {
                p = (float)exp(-(double)de);
            }
            lt = rv[j] < p;
        }
        const bool flip = lt && (dv[j] > 0.5f);
        o[j] = flip ? -s : s;
    }
    return o;
}

__global__ __launch_bounds__(256) void ising_flip_kernel(
    const float* __restrict__ x,
    const float* __restrict__ rnd,
    const float* __restrict__ drop,
    float* __restrict__ out)
{
    // Unit decode: unit = (xcd*512 + B>>3); each XCD owns a contiguous range
    // of (image, group, half) units -> exactly 2 images per XCD.
    const int B    = blockIdx.x;
    const int unit = (B & 7) * 512 + (B >> 3);
    const int half = unit & 1;
    const int gi   = unit >> 1;            // 0..2047 = b*128 + g
    const int b    = gi >> 7;              // image
    const int g    = gi & 127;             // 16-row group within image

    const int c0   = half * 1024 + (int)threadIdx.x * 4;
    const int lane = (int)threadIdx.x & 63;

    const size_t img = (size_t)b * IMG;
    const float* xi  = x + img;
    const int cl = (c0 == 0)      ? (Wn - 1) : (c0 - 1);
    const int cr = (c0 + 4 == Wn) ? 0        : (c0 + 4);

    int h0 = g * 16;

    // Prologue: 6 x rows (h0-1..h0+4) + current rand rows.
    f4 r[6];
#pragma unroll
    for (int k = 0; k < 6; ++k)
        r[k] = *(const f4*)(xi + (size_t)wrapr(h0 - 1 + k) * Wn + c0);
    f4 rv[4];
#pragma unroll
    for (int i = 0; i < 4; ++i)
        rv[i] = __builtin_nontemporal_load(
            (const f4*)(rnd + img + (size_t)(h0 + i) * Wn + c0));

#pragma unroll
    for (int t = 0; t < 4; ++t) {
        // Prefetch next strip (x rows h0+5..h0+8, rand rows h0+4..h0+7)
        // BEFORE computing current -> latency hides under flip_row work.
        f4 nx[4], nrv[4];
        if (t < 3) {
#pragma unroll
            for (int k = 0; k < 4; ++k)
                nx[k] = *(const f4*)(xi + (size_t)wrapr(h0 + 5 + k) * Wn + c0);
#pragma unroll
            for (int i = 0; i < 4; ++i)
                nrv[i] = __builtin_nontemporal_load(
                    (const f4*)(rnd + img + (size_t)(h0 + 4 + i) * Wn + c0));
        }

        // Halo columns via wave shuffles; wave-edge lanes load the scalar.
        float lf[4], rt[4];
#pragma unroll
        for (int i = 0; i < 4; ++i) {
            lf[i] = __shfl_up(r[i + 1][3], 1);
            rt[i] = __shfl_down(r[i + 1][0], 1);
        }
        if (lane == 0) {
#pragma unroll
            for (int i = 0; i < 4; ++i) lf[i] = xi[(size_t)(h0 + i) * Wn + cl];
        }
        if (lane == 63) {
#pragma unroll
            for (int i = 0; i < 4; ++i) rt[i] = xi[(size_t)(h0 + i) * Wn + cr];
        }

#pragma unroll
        for (int i = 0; i < 4; ++i) {
            const f4 dv = *(const f4*)(drop + (size_t)(h0 + i) * Wn + c0);
            const f4 o  = flip_row(r[i], r[i + 1], r[i + 2], rv[i], dv,
                                   lf[i], rt[i]);
            __builtin_nontemporal_store(
                o, (f4*)(out + img + (size_t)(h0 + i) * Wn + c0));
        }

        if (t < 3) {
            // Roll: 2 boundary rows carry over in registers.
            r[0] = r[4];
            r[1] = r[5];
#pragma unroll
            for (int k = 0; k < 4; ++k) r[2 + k] = nx[k];
#pragma unroll
            for (int i = 0; i < 4; ++i) rv[i] = nrv[i];
            h0 += 4;
        }
    }
}

} // namespace

extern "C" void kernel_launch(void* const* d_in, const int* in_sizes, int n_in,
                              void* d_out, int out_size, void* d_ws, size_t ws_size,
                              hipStream_t stream)
{
    const float* x    = (const float*)d_in[0];
    const float* rnd  = (const float*)d_in[1];
    const float* drop = (const float*)d_in[2];
    float* out        = (float*)d_out;

    hipLaunchKernelGGL(ising_flip_kernel, dim3(NBLK), dim3(256), 0, stream,
                       x, rnd, drop, out);
}

// Round 6
// 153.510 us; speedup vs baseline: 1.0791x; 1.0791x over previous
//
#include <hip/hip_runtime.h>
#include <math.h>

// Ising-style flip: out = s * flip where
//   Js = up+down+left+right (periodic, r=1); de = (2*s)*Js
//   p  = de<=0 ? 1 : exp(-de); flip = (rand<p)&&(drop>0.5) ? -1 : +1
// x, rand: (16,1,2048,2048) f32; drop: (2048,2048) f32.
//
// R6: exact R3 geometry (best: 151us), single isolated change -> regular
// stores instead of nontemporal (A/B the NT-store hint, which was never
// isolated). NT rand loads kept (protect x L3 residency).

namespace {

constexpr int Bn  = 16;
constexpr int Hn  = 2048;
constexpr int Wn  = 2048;
constexpr int W4  = Wn / 4;             // 512 float4 per row
constexpr int RPT = 4;                  // rows per thread
constexpr int HS  = Hn / RPT;           // 512 strips per image
constexpr int NTHREADS = Bn * HS * W4;  // 4,194,304
constexpr int NBLK = NTHREADS / 256;    // 16,384
constexpr int NXCD = 8;
constexpr int BLK_PER_XCD = NBLK / NXCD; // 2048

typedef float f4 __attribute__((ext_vector_type(4)));

__global__ __launch_bounds__(256) void ising_flip_kernel(
    const float* __restrict__ x,
    const float* __restrict__ rnd,
    const float* __restrict__ drop,
    float* __restrict__ out)
{
    // XCD swizzle: physical block b lands on XCD b%8 (round-robin dispatch).
    // Map so each XCD owns a contiguous logical chunk -> vertical neighbors
    // share that XCD's L2.
    const int phys    = blockIdx.x;
    const int logical = (phys & (NXCD - 1)) * BLK_PER_XCD + (phys >> 3);
    const int tid     = logical * 256 + (int)threadIdx.x;
    const int lane    = (int)threadIdx.x & 63;

    const int wv = tid & (W4 - 1);          // col-vec, fastest (coalesced)
    const int hs = (tid >> 9) & (HS - 1);   // row strip
    const int b  = tid >> 18;               // image

    const int    c0  = wv * 4;
    const int    h0  = hs * RPT;
    const size_t img = (size_t)b * (size_t)(Hn * Wn);
    const float* xi  = x + img;

    // 6 x-rows cover 4 output rows (+1 up, +1 down). Only k=0 / k=5 can wrap.
    f4 xr[RPT + 2];
#pragma unroll
    for (int k = 0; k < RPT + 2; ++k) {
        int hr = h0 - 1 + k;
        hr = (hr < 0) ? (Hn - 1) : ((hr >= Hn) ? 0 : hr);
        xr[k] = *(const f4*)(xi + (size_t)hr * Wn + c0);
    }

    f4 rv[RPT], dv[RPT];
#pragma unroll
    for (int i = 0; i < RPT; ++i) {
        const int row = (h0 + i) * Wn;
        rv[i] = __builtin_nontemporal_load((const f4*)(rnd + img + row + c0));
        dv[i] = *(const f4*)(drop + row + c0);
    }

    // Halo columns: neighbor lane already holds them. Lane l's left scalar is
    // lane l-1's xr[i+1][3]; right scalar is lane l+1's xr[i+1][0]. Only the
    // wave-edge lanes (0 / 63) need a real load (also covers the W-wrap).
    float lf[RPT], rt[RPT];
#pragma unroll
    for (int i = 0; i < RPT; ++i) {
        lf[i] = __shfl_up(xr[i + 1][3], 1);
        rt[i] = __shfl_down(xr[i + 1][0], 1);
    }
    if (lane == 0) {
        const int cl = (c0 == 0) ? (Wn - 1) : (c0 - 1);
#pragma unroll
        for (int i = 0; i < RPT; ++i) lf[i] = xi[(h0 + i) * Wn + cl];
    }
    if (lane == 63) {
        const int cr = (c0 + 4 == Wn) ? 0 : (c0 + 4);
#pragma unroll
        for (int i = 0; i < RPT; ++i) rt[i] = xi[(h0 + i) * Wn + cr];
    }

#pragma unroll
    for (int i = 0; i < RPT; ++i) {
        const f4 sc = xr[i + 1];
        const f4 up = xr[i];
        const f4 dn = xr[i + 2];
        f4 o;
#pragma unroll
        for (int j = 0; j < 4; ++j) {
            const float s     = sc[j];
            const float left  = (j == 0) ? lf[i] : sc[j - 1];
            const float right = (j == 3) ? rt[i] : sc[j + 1];
            // Reference op order: Js = ((up+down)+left)+right; de = (2*s)*Js
            const float js = ((up[j] + dn[j]) + left) + right;
            const float de = (2.0f * s) * js;

            bool lt;
            if (de <= 0.0f) {
                lt = true;                    // p = 1; rand in [0,1) < 1
            } else {
                float p = expf(-de);
                // Tie band: near-equal rand vs p -> recompute exp in double
                // to match the host reference's correctly-rounded decision.
                if (fabsf(rv[i][j] - p) <= p * 1.0e-6f) {
                    p = (float)exp(-(double)de);
                }
                lt = rv[i][j] < p;
            }
            const bool flip = lt && (dv[i][j] > 0.5f);
            o[j] = flip ? -s : s;
        }
        *(f4*)(out + img + (size_t)(h0 + i) * Wn + c0) = o;   // regular store
    }
}

} // namespace

extern "C" void kernel_launch(void* const* d_in, const int* in_sizes, int n_in,
                              void* d_out, int out_size, void* d_ws, size_t ws_size,
                              hipStream_t stream)
{
    const float* x    = (const float*)d_in[0];
    const float* rnd  = (const float*)d_in[1];
    const float* drop = (const float*)d_in[2];
    float* out        = (float*)d_out;

    hipLaunchKernelGGL(ising_flip_kernel, dim3(NBLK), dim3(256), 0, stream,
                       x, rnd, drop, out);
}